// Round 1
// baseline (139.553 us; speedup 1.0000x reference)
//
#include <hip/hip_runtime.h>

// SMPL forward, all I/O fp32. B=512, V=6890, J=24, NS=10, NP=207.
//
// Full path (ws >= 10.38MB), 3 launches:
//  k_prep : partitioned grid: [0,192) jreg partial folds (LDS-staged sd);
//           [192,2460) posedirs->BT bf16; [2460,2487) weights->WT bf16
//  k_chain: Rodrigues + level-parallel chain + G=rot*A; 4 bodies/block;
//           emits A1 (pf|shapes) + A2 (G) fragment-major bf16
//  k_fused: B-register-resident MFMA GEMM1+GEMM2 + fp32 epilogue -> out (m-loop x8)
// Fallback (small ws): round-2 fused k_main.

#define BN 512
#define NV 6890
#define NVP 6912        // padded V (216 x 32)
#define NJ 24
#define NS 10
#define NP 207
#define PSTR 208
#define KP 224          // padded K for GEMM1 (207 pf + 10 shapes + 7 pad)
#define NPAD 20736      // 3*NVP
#define BB 8
#define TV 256

// fallback ws layout (float offsets)
#define WS_JSP 0                      // 24*8*33 = 6336
#define WS_G   6400                   // 512*288 (fallback only)
#define WS_PF  153856                 // 512*208 (fallback only)
// full-path u16 offsets (after JSP: 6400 floats = 12800 u16)
#define WS_A1  12800                  // 28*512*8  = 114688 -> 127488
#define WS_A2  127488                 // 12*4*512*8= 196608 -> 324096
#define WS_WT  324096                 // 4*6912*8  = 221184 -> 545280
#define WS_BT  545280                 // 3*28*6912*8 = 4644864 -> 5190144 u16
#define FULL_NEED ((size_t)10380288)

typedef unsigned short u16;
typedef short bf16x8 __attribute__((ext_vector_type(8)));
typedef float f32x4  __attribute__((ext_vector_type(4)));

__constant__ int c_par[NJ] = {-1,0,0,0,1,2,3,4,5,6,7,8,9,9,9,12,13,14,16,17,18,19,20,21};
// kinematic tree levels (depth 1..8); joints at equal depth are independent
__constant__ int c_lvl_joint[23] = {1,2,3, 4,5,6, 7,8,9, 10,11,12,13,14, 15,16,17, 18,19, 20,21, 22,23};
__constant__ int c_lvl_off[9]    = {0,3,6,9,14,17,19,21,23};

__device__ __forceinline__ u16 f2bf(float f){
    union { float f; unsigned i; } x; x.f = f;
    unsigned r = x.i + 0x7fffu + ((x.i >> 16) & 1u);   // RNE
    return (u16)(r >> 16);
}

// ---------------- k_prep: jreg partials (192) | BT conv (2268) | WT conv (27) ----------------
__global__ __launch_bounds__(256) void k_prep(const float* __restrict__ jreg,
                                              const float* __restrict__ vt,
                                              const float* __restrict__ sd,
                                              const float* __restrict__ pd,
                                              const float* __restrict__ wts,
                                              float* __restrict__ ws,
                                              u16* __restrict__ bt,
                                              u16* __restrict__ wt,
                                              int full){
    __shared__ __align__(16) float s_red[4][33];
    __shared__ __align__(16) u16 s_tile[32][65];
    __shared__ __align__(16) float s_sd[256*30];   // staged shapedirs chunk
    int bid = blockIdx.x;
    int t = threadIdx.x;

    if(bid < 192){
        // ---- J_regressor partial folds (LDS-staged sd for coalescing) ----
        int j = bid >> 3, s = bid & 7;
        int v0 = s*864, v1 = min(NV, v0+864);
        float acc[33];
        #pragma unroll
        for(int k=0;k<33;k++) acc[k]=0.f;
        for(int c0=v0; c0<v1; c0+=256){
            int nv = min(256, v1-c0);
            // stage sd[c0*30 .. c0*30+nv*30) contiguously (float4, fully coalesced)
            int nf4 = (nv*30) >> 2;
            const float4* src = (const float4*)(sd + (size_t)c0*30);
            for(int i=t; i<nf4; i+=256) ((float4*)s_sd)[i] = src[i];
            __syncthreads();
            if(t<nv){
                int v = c0 + t;
                float jr = jreg[j*NV+v];
                #pragma unroll
                for(int d=0;d<3;d++) acc[d] = fmaf(jr, vt[v*3+d], acc[d]);
                const float* sp = &s_sd[t*30];
                #pragma unroll
                for(int k=0;k<30;k++) acc[3+k] = fmaf(jr, sp[k], acc[3+k]);
            }
            __syncthreads();   // before next chunk overwrites s_sd
        }
        int lane = t & 63, wv = t >> 6;
        #pragma unroll
        for(int k=0;k<33;k++){
            float val = acc[k];
            #pragma unroll
            for(int off=32; off; off>>=1) val += __shfl_down(val, off, 64);
            if(lane==0) s_red[wv][k]=val;
        }
        __syncthreads();
        if(t<33) ws[WS_JSP + (j*8+s)*33 + t] = s_red[0][t]+s_red[1][t]+s_red[2][t]+s_red[3][t];
    } else if(bid < 2460){
        // ---- posedirs|shapedirs -> BT[d][chunk][v][8] bf16 ----
        if(!full) return;
        int bid2 = bid - 192;
        int n0 = (bid2 % 324) * 64;
        int k0 = (bid2 / 324) * 32;
        int nl = t & 63, kb = (t>>6)*8;
        int n = n0 + nl;
        #pragma unroll
        for(int i=0;i<8;i++){
            int k = k0 + kb + i;
            float v = 0.f;
            if(n < NV*3){
                if(k < NP)           v = pd[(size_t)k*(NV*3) + n];
                else if(k < NP+NS)   v = sd[(size_t)(n/3)*30 + (n%3)*10 + (k-NP)];
            }
            s_tile[kb+i][nl] = f2bf(v);
        }
        __syncthreads();
        int nl2 = t >> 2, kc = t & 3;
        union { u16 s[8]; uint4 q; } u;
        #pragma unroll
        for(int i=0;i<8;i++) u.s[i] = s_tile[kc*8+i][nl2];
        int ng = n0 + nl2;
        int v = ng/3, d = ng%3;
        int chunk = (k0>>3) + kc;
        *(uint4*)(bt + (((size_t)d*28 + chunk)*NVP + v)*8) = u.q;
    } else {
        // ---- weights -> WT[chunk][v][8] bf16 ----
        if(!full) return;
        int v = (bid - 2460)*256 + t;
        if(v >= NVP) return;
        union { u16 s[32]; uint4 q[4]; } u;
        #pragma unroll
        for(int j=0;j<24;j++) u.s[j] = (v<NV) ? f2bf(wts[(size_t)v*24+j]) : (u16)0;
        #pragma unroll
        for(int j=24;j<32;j++) u.s[j]=0;
        #pragma unroll
        for(int c=0;c<4;c++)
            *(uint4*)(wt + ((size_t)c*NVP + v)*8) = u.q[c];
    }
}

// ---------------- k_chain: rodrigues + level-parallel chain + G + A1/A2 emit ----------------
// 4 bodies per block (one per wave); jreg fold loaded once per block.
__global__ __launch_bounds__(256) void k_chain(const float* __restrict__ poses,
                                               const float* __restrict__ shapes,
                                               const float* __restrict__ Rh,
                                               float* __restrict__ ws,
                                               u16* __restrict__ a1,
                                               u16* __restrict__ a2,
                                               int full){
    int tid  = threadIdx.x;
    int w    = tid >> 6;
    int lane = tid & 63;
    int b    = blockIdx.x*4 + w;

    __shared__ float js[792];
    __shared__ float R[4][25][9];
    __shared__ float sh[4][NS];
    __shared__ float jrest[4][NJ][3];
    __shared__ float rel[4][NJ][3];
    __shared__ float chR[4][NJ][9];
    __shared__ float chT[4][NJ][3];
    __shared__ float Gs[4][NJ][12];

    // block-shared jreg fold (finish the 8 partials)
    for(int idx=tid; idx<792; idx+=256){
        int j = idx/33, e = idx%33;
        float a = 0.f;
        #pragma unroll
        for(int s=0;s<8;s++) a += ws[WS_JSP + (j*8+s)*33 + e];
        js[idx]=a;
    }
    // Rodrigues (per wave: 24 pose joints + Rh)
    if(lane<25){
        float x,y,z;
        if(lane<24){ x=poses[b*72+lane*3]; y=poses[b*72+lane*3+1]; z=poses[b*72+lane*3+2]; }
        else       { x=Rh[b*3];            y=Rh[b*3+1];            z=Rh[b*3+2]; }
        float ax=x+1e-8f, ay=y+1e-8f, az=z+1e-8f;
        float ang = sqrtf(ax*ax+ay*ay+az*az);
        float inv = 1.f/ang;
        float rx=x*inv, ry=y*inv, rz=z*inv;
        float s = sinf(ang), c = cosf(ang), oc = 1.f - c;
        R[w][lane][0]=1.f+oc*(-rz*rz-ry*ry); R[w][lane][1]=-s*rz+oc*(rx*ry);      R[w][lane][2]= s*ry+oc*(rx*rz);
        R[w][lane][3]= s*rz+oc*(rx*ry);      R[w][lane][4]=1.f+oc*(-rz*rz-rx*rx); R[w][lane][5]=-s*rx+oc*(ry*rz);
        R[w][lane][6]=-s*ry+oc*(rx*rz);      R[w][lane][7]= s*rx+oc*(ry*rz);      R[w][lane][8]=1.f+oc*(-ry*ry-rx*rx);
    }
    if(lane<NS) sh[w][lane]=shapes[b*NS+lane];
    __syncthreads();

    // pose feature -> A1 (full, fragment-major) or ws PF (fallback)
    for(int idx=lane; idx<KP; idx+=64){
        float v = 0.f;
        if(idx<NP){
            int j = 1 + idx/9, e = idx%9;
            v = R[w][j][e] - ((e==0||e==4||e==8)?1.f:0.f);
        } else if(idx<NP+NS) v = sh[w][idx-NP];
        if(full){ a1[(((size_t)(idx>>3))*BN + b)*8 + (idx&7)] = f2bf(v); }
        else if(idx<PSTR) ws[WS_PF + b*PSTR + idx] = (idx<NP)?v:0.f;
    }
    if(lane<NJ){
        #pragma unroll
        for(int d=0;d<3;d++){
            float a = js[lane*33 + d];
            #pragma unroll
            for(int l=0;l<NS;l++) a = fmaf(sh[w][l], js[lane*33 + 3 + d*10 + l], a);
            jrest[w][lane][d]=a;
        }
    }
    __syncthreads();
    if(lane<NJ){
        int p = c_par[lane];
        #pragma unroll
        for(int d=0;d<3;d++) rel[w][lane][d] = (lane==0) ? jrest[w][0][d] : jrest[w][lane][d]-jrest[w][p][d];
    }
    __syncthreads();
    if(lane<9) chR[w][0][lane]=R[w][0][lane];
    if(lane<3) chT[w][0][lane]=rel[w][0][lane];
    __syncthreads();
    // level-parallel chain: 8 steps, joints at equal tree depth in parallel
    #pragma unroll
    for(int L=0; L<8; L++){
        int o = c_lvl_off[L];
        int n = c_lvl_off[L+1]-o;
        if(lane < n*12){
            int ji = c_lvl_joint[o + lane/12];
            int t12 = lane - (lane/12)*12;
            int r = t12>>2, cc = t12&3, p = c_par[ji];
            if(cc<3){
                chR[w][ji][r*3+cc] = chR[w][p][r*3+0]*R[w][ji][0*3+cc]
                                   + chR[w][p][r*3+1]*R[w][ji][1*3+cc]
                                   + chR[w][p][r*3+2]*R[w][ji][2*3+cc];
            } else {
                chT[w][ji][r] = chR[w][p][r*3+0]*rel[w][ji][0]
                              + chR[w][p][r*3+1]*rel[w][ji][1]
                              + chR[w][p][r*3+2]*rel[w][ji][2] + chT[w][p][r];
            }
        }
        __syncthreads();
    }
    if(lane<NJ){
        float rg[9];
        #pragma unroll
        for(int k=0;k<9;k++) rg[k]=R[w][24][k];
        float at[3];
        #pragma unroll
        for(int r=0;r<3;r++){
            float tj = chR[w][lane][r*3+0]*jrest[w][lane][0]
                     + chR[w][lane][r*3+1]*jrest[w][lane][1]
                     + chR[w][lane][r*3+2]*jrest[w][lane][2];
            at[r] = chT[w][lane][r] - tj;
        }
        #pragma unroll
        for(int r=0;r<3;r++){
            #pragma unroll
            for(int cc=0;cc<3;cc++)
                Gs[w][lane][r*4+cc] = rg[r*3+0]*chR[w][lane][0*3+cc]
                                    + rg[r*3+1]*chR[w][lane][1*3+cc]
                                    + rg[r*3+2]*chR[w][lane][2*3+cc];
            Gs[w][lane][r*4+3] = rg[r*3+0]*at[0] + rg[r*3+1]*at[1] + rg[r*3+2]*at[2];
        }
    }
    __syncthreads();
    if(full){
        // A2[e][chunk][b][8] = bf16(G[b][j=k][e]), pad k>=24 -> 0
        for(int idx=lane; idx<12*32; idx+=64){
            int e = idx>>5, k = idx&31;
            float v = (k<NJ) ? Gs[w][k][e] : 0.f;
            a2[((((size_t)e*4)+(k>>3))*BN + b)*8 + (k&7)] = f2bf(v);
        }
    } else if(lane<NJ){
        float* g = &ws[WS_G + b*288 + lane*12];
        #pragma unroll
        for(int e=0;e<12;e++) g[e] = Gs[w][lane][e];
    }
}

// ---------------- k_fused: B-resident GEMM1 + GEMM2 + epilogue, m-loop x8 ----------------
__global__ __launch_bounds__(256) void k_fused(const u16* __restrict__ A1,
                                               const u16* __restrict__ A2,
                                               const u16* __restrict__ WT,
                                               const u16* __restrict__ BT,
                                               const float* __restrict__ vt,
                                               const float* __restrict__ th,
                                               float* __restrict__ out){
    int t = threadIdx.x;
    int w = t>>6, lane = t&63;
    int quad = lane>>4, l16 = lane&15;
    int v = blockIdx.y*64 + w*16 + l16;

    // held fragments: B (3 comps x 7 k-slices), weights
    bf16x8 Bf[3][7];
    #pragma unroll
    for(int d=0;d<3;d++)
        #pragma unroll
        for(int s=0;s<7;s++)
            Bf[d][s] = *(const bf16x8*)(BT + (((size_t)d*28 + s*4 + quad)*NVP + v)*8);
    bf16x8 wf = *(const bf16x8*)(WT + ((size_t)quad*NVP + v)*8);
    float vt0=0.f, vt1=0.f, vt2=0.f;
    if(v<NV){ vt0=vt[v*3]; vt1=vt[v*3+1]; vt2=vt[v*3+2]; }
    f32x4 zz = {0.f,0.f,0.f,0.f};

    #pragma unroll 1
    for(int mi=0;mi<8;mi++){
        int m0 = blockIdx.x*128 + mi*16;
        int mrow = m0 + l16;
        f32x4 accP0=zz, accP1=zz, accP2=zz;
        #pragma unroll
        for(int s=0;s<7;s++){
            bf16x8 af = *(const bf16x8*)(A1 + (((size_t)s*4 + quad)*BN + mrow)*8);
            accP0 = __builtin_amdgcn_mfma_f32_16x16x32_bf16(af, Bf[0][s], accP0, 0,0,0);
            accP1 = __builtin_amdgcn_mfma_f32_16x16x32_bf16(af, Bf[1][s], accP1, 0,0,0);
            accP2 = __builtin_amdgcn_mfma_f32_16x16x32_bf16(af, Bf[2][s], accP2, 0,0,0);
        }
        f32x4 accT[12];
        #pragma unroll
        for(int e=0;e<12;e++){
            bf16x8 gf = *(const bf16x8*)(A2 + (((size_t)e*4 + quad)*BN + mrow)*8);
            accT[e] = __builtin_amdgcn_mfma_f32_16x16x32_bf16(gf, wf, zz, 0,0,0);
        }
        if(v < NV){
            #pragma unroll
            for(int r=0;r<4;r++){
                int b = m0 + quad*4 + r;
                float t0 = th[b*3+0], t1 = th[b*3+1], t2 = th[b*3+2];
                float p0 = accP0[r] + vt0;
                float p1 = accP1[r] + vt1;
                float p2 = accP2[r] + vt2;
                float o0 = fmaf(accT[0][r],p0, fmaf(accT[1][r],p1, fmaf(accT[2][r], p2, accT[3][r]))) + t0;
                float o1 = fmaf(accT[4][r],p0, fmaf(accT[5][r],p1, fmaf(accT[6][r], p2, accT[7][r]))) + t1;
                float o2 = fmaf(accT[8][r],p0, fmaf(accT[9][r],p1, fmaf(accT[10][r],p2, accT[11][r]))) + t2;
                float* op = out + ((size_t)b*NV + v)*3;
                op[0]=o0; op[1]=o1; op[2]=o2;
            }
        }
    }
}

// ---------------- fallback: round-2 fused k_main ----------------
__global__ __launch_bounds__(256) void k_main(const float* __restrict__ vt,
                                              const float* __restrict__ sd,
                                              const float* __restrict__ pd,
                                              const float* __restrict__ wts,
                                              const float* __restrict__ th,
                                              const float* __restrict__ shapes,
                                              const float* __restrict__ ws,
                                              float* __restrict__ out){
    __shared__ __align__(16) float pf_s[BB*PSTR];
    __shared__ __align__(16) float g_s[BB*288];
    __shared__ float th_s[BB*3];
    __shared__ float sh_s[BB*NS];
    int tid = threadIdx.x;
    int b0  = blockIdx.y * BB;
    int v   = blockIdx.x * TV + tid;

    for(int i=tid; i<BB*PSTR; i+=TV) pf_s[i] = ws[WS_PF + b0*PSTR + i];
    for(int i=tid; i<BB*288;  i+=TV) g_s[i]  = ws[WS_G  + b0*288  + i];
    if(tid<BB*3)  th_s[tid] = th[b0*3+tid];
    if(tid<BB*NS) sh_s[tid] = shapes[b0*NS+tid];
    __syncthreads();
    if(v>=NV) return;

    float sdv[30];
    {
        const float2* sp = (const float2*)(sd + (size_t)v*30);
        #pragma unroll
        for(int i=0;i<15;i++){ float2 s2 = sp[i]; sdv[2*i]=s2.x; sdv[2*i+1]=s2.y; }
    }
    float vt0=vt[v*3], vt1=vt[v*3+1], vt2=vt[v*3+2];
    float vp[BB][3];
    #pragma unroll
    for(int b=0;b<BB;b++){
        #pragma unroll
        for(int d=0;d<3;d++){
            float a = (d==0)?vt0:((d==1)?vt1:vt2);
            #pragma unroll
            for(int l=0;l<NS;l++) a = fmaf(sh_s[b*NS+l], sdv[d*10+l], a);
            vp[b][d]=a;
        }
    }
    const float* pcol = pd + (size_t)v*3;
    int p=0;
    for(; p<=NP-4; p+=4){
        float pdv[4][3];
        #pragma unroll
        for(int q=0;q<4;q++){
            size_t base = (size_t)(p+q)*(NV*3);
            pdv[q][0]=pcol[base]; pdv[q][1]=pcol[base+1]; pdv[q][2]=pcol[base+2];
        }
        #pragma unroll
        for(int b=0;b<BB;b++){
            float4 f = *(const float4*)&pf_s[b*PSTR+p];
            #pragma unroll
            for(int d=0;d<3;d++)
                vp[b][d] = fmaf(f.x,pdv[0][d], fmaf(f.y,pdv[1][d], fmaf(f.z,pdv[2][d], fmaf(f.w,pdv[3][d], vp[b][d]))));
        }
    }
    for(; p<NP; p++){
        size_t base=(size_t)p*(NV*3);
        float p0=pcol[base], p1=pcol[base+1], p2=pcol[base+2];
        #pragma unroll
        for(int b=0;b<BB;b++){
            float f = pf_s[b*PSTR+p];
            vp[b][0]=fmaf(f,p0,vp[b][0]); vp[b][1]=fmaf(f,p1,vp[b][1]); vp[b][2]=fmaf(f,p2,vp[b][2]);
        }
    }
    float w[24];
    {
        const float4* wp = (const float4*)(wts + (size_t)v*24);
        #pragma unroll
        for(int i=0;i<6;i++){
            float4 u = wp[i];
            w[i*4+0]=u.x; w[i*4+1]=u.y; w[i*4+2]=u.z; w[i*4+3]=u.w;
        }
    }
    #pragma unroll 1
    for(int b=0;b<BB;b++){
        float4 T0=make_float4(0.f,0.f,0.f,0.f), T1=T0, T2=T0;
        #pragma unroll
        for(int j=0;j<NJ;j++){
            float wj = w[j];
            const float4* g = (const float4*)&g_s[b*288 + j*12];
            float4 g0=g[0], g1=g[1], g2=g[2];
            T0.x=fmaf(wj,g0.x,T0.x); T0.y=fmaf(wj,g0.y,T0.y); T0.z=fmaf(wj,g0.z,T0.z); T0.w=fmaf(wj,g0.w,T0.w);
            T1.x=fmaf(wj,g1.x,T1.x); T1.y=fmaf(wj,g1.y,T1.y); T1.z=fmaf(wj,g1.z,T1.z); T1.w=fmaf(wj,g1.w,T1.w);
            T2.x=fmaf(wj,g2.x,T2.x); T2.y=fmaf(wj,g2.y,T2.y); T2.z=fmaf(wj,g2.z,T2.z); T2.w=fmaf(wj,g2.w,T2.w);
        }
        float x=vp[b][0], y=vp[b][1], z=vp[b][2];
        float ox = fmaf(T0.x,x, fmaf(T0.y,y, fmaf(T0.z,z, T0.w))) + th_s[b*3+0];
        float oy = fmaf(T1.x,x, fmaf(T1.y,y, fmaf(T1.z,z, T1.w))) + th_s[b*3+1];
        float oz = fmaf(T2.x,x, fmaf(T2.y,y, fmaf(T2.z,z, T2.w))) + th_s[b*3+2];
        size_t o = ((size_t)(b0+b)*NV + v)*3;
        out[o]=ox; out[o+1]=oy; out[o+2]=oz;
    }
}

extern "C" void kernel_launch(void* const* d_in, const int* in_sizes, int n_in,
                              void* d_out, int out_size, void* d_ws, size_t ws_size,
                              hipStream_t stream){
    const float* poses  = (const float*)d_in[0];
    const float* shapes = (const float*)d_in[1];
    const float* Rh     = (const float*)d_in[2];
    const float* Th     = (const float*)d_in[3];
    const float* vt     = (const float*)d_in[4];
    const float* sd     = (const float*)d_in[5];
    const float* pdirs  = (const float*)d_in[6];
    const float* jreg   = (const float*)d_in[7];
    const float* wts    = (const float*)d_in[8];
    float* ws  = (float*)d_ws;
    float* out = (float*)d_out;
    u16* u = (u16*)d_ws;
    int full = (ws_size >= FULL_NEED) ? 1 : 0;

    hipLaunchKernelGGL(k_prep, dim3(2487), dim3(256), 0, stream,
                       jreg, vt, sd, pdirs, wts, ws, u + WS_BT, u + WS_WT, full);
    hipLaunchKernelGGL(k_chain, dim3(BN/4), dim3(256), 0, stream, poses, shapes, Rh, ws,
                       u + WS_A1, u + WS_A2, full);
    if(full){
        hipLaunchKernelGGL(k_fused, dim3(BN/128, NVP/64), dim3(256), 0, stream,
                           u + WS_A1, u + WS_A2, u + WS_WT, u + WS_BT, vt, Th, out);
    } else {
        hipLaunchKernelGGL(k_main, dim3((NV+TV-1)/TV, BN/BB), dim3(256), 0, stream,
                           vt, sd, pdirs, wts, Th, shapes, ws, out);
    }
}